// Round 1
// baseline (120.120 us; speedup 1.0000x reference)
//
#include <hip/hip_runtime.h>
#include <hip/hip_bf16.h>
#include <stdint.h>

#define BATCH    512
#define IN_DIM   256
#define OUT_DIM  256
#define COND_DIM 128
#define HIDDEN   128
#define W2_COLS  65792      // 256*257
#define H_STRIDE 132
#define PLANE_SZ 65536      // shorts per transposed bf16 plane [o][i]
#define NCHUNKS  18         // 16x8-plane + {b2w,bw} + bias
#define OUT_ELEMS (BATCH * OUT_DIM)
#define SLICE_OFF ((size_t)131 * PLANE_SZ)   // shorts: slices after 131 planes

typedef __attribute__((ext_vector_type(8))) short bf16x8;
typedef __attribute__((ext_vector_type(4))) float f32x4;

__device__ float          g_h[BATCH * H_STRIDE + 8];   // f32 h (+1.0 planes), padded
__device__ unsigned short g_hbf[BATCH * HIDDEN];       // bf16 h for bias-chunk A frags
__device__ unsigned short g_xbf[BATCH * IN_DIM];       // bf16 x for A frags

static __device__ __forceinline__ unsigned short f2bf(float f) {
    union { float f; unsigned int u; } v; v.f = f;
    unsigned int r = v.u + 0x7FFFu + ((v.u >> 16) & 1u);  // RNE
    return (unsigned short)(r >> 16);
}
static __device__ __forceinline__ unsigned int pack2(float a, float b) {
    return (unsigned int)f2bf(a) | ((unsigned int)f2bf(b) << 16);
}
static __device__ __forceinline__ float bf2f(unsigned short u) {
    union { unsigned int u; float f; } v; v.u = ((unsigned int)u) << 16;
    return v.f;
}

template<int N>
static __device__ __forceinline__ void wait_vmcnt() {
    if constexpr (N == 0)      asm volatile("s_waitcnt vmcnt(0)" ::: "memory");
    else if constexpr (N == 2) asm volatile("s_waitcnt vmcnt(2)" ::: "memory");
    else                       asm volatile("s_waitcnt vmcnt(4)" ::: "memory");
}

// ---------------- prep: convert/transpose planes + x,h ---------------------
// grid: [0,2080) w2/b2/bw plane tiles; [2080,2088) bias-col tiles;
//       [2088,2104) x convert; [2104,2360) h compute (2 rows/block)
__global__ __launch_bounds__(256)
void hyper_prep_kernel(const float* __restrict__ x,
                       const float* __restrict__ cond,
                       const float* __restrict__ base_weight,
                       const float* __restrict__ w1,
                       const float* __restrict__ b1,
                       const float* __restrict__ w2,
                       const float* __restrict__ b2,
                       unsigned short* __restrict__ wt) {
    const int bx = blockIdx.x;
    const int t  = threadIdx.x;
    if (bx < 2088) {
        int p, it, ot; const float* src; int rstride;
        if (bx < 2080) {
            p = bx >> 4; int sub = bx & 15; it = sub >> 2; ot = sub & 3;
            src = (p < 128) ? (w2 + (size_t)p * W2_COLS) : (p == 128 ? b2 : base_weight);
            rstride = OUT_DIM;
        } else {
            p = 130; int sub = bx - 2080; it = sub >> 2; ot = sub & 3;   // it 0..1 (k<128)
            src = w2 + 65536; rstride = W2_COLS;
        }
        int o  = ot * 64 + (t & 63);
        int i0 = it * 64 + (t >> 6) * 16;
        unsigned int vv[8];
        #pragma unroll
        for (int r = 0; r < 8; ++r) {
            float a = src[(size_t)(i0 + 2 * r)     * rstride + o];
            float b = src[(size_t)(i0 + 2 * r + 1) * rstride + o];
            vv[r] = pack2(a, b);
        }
        unsigned int* dst = (unsigned int*)(wt + (size_t)p * PLANE_SZ + (size_t)o * 256 + i0);
        *(uint4*)dst       = *(uint4*)&vv[0];
        *(uint4*)(dst + 4) = *(uint4*)&vv[4];
    } else if (bx < 2104) {
        int base = (bx - 2088) * 8192 + t * 32;
        #pragma unroll
        for (int g = 0; g < 4; ++g) {
            const float4* s4 = (const float4*)(x + base + g * 8);
            float4 a = s4[0], b = s4[1];
            unsigned int vv[4] = { pack2(a.x, a.y), pack2(a.z, a.w),
                                   pack2(b.x, b.y), pack2(b.z, b.w) };
            *(uint4*)(g_xbf + base + g * 8) = *(uint4*)vv;
        }
    } else {
        __shared__ float c[2][COND_DIM];
        int bb = t >> 7, k = t & 127;
        int b  = (bx - 2104) * 2 + bb;
        c[bb][k] = cond[b * COND_DIM + k];
        __syncthreads();
        float acc = b1[k];
        #pragma unroll 8
        for (int i = 0; i < COND_DIM; ++i)
            acc += c[bb][i] * w1[i * HIDDEN + k];
        acc = fmaxf(acc, 0.0f);
        g_h[b * H_STRIDE + k] = acc;
        g_hbf[b * HIDDEN + k] = f2bf(acc);
        if (k < 4) g_h[b * H_STRIDE + 128 + k] = 1.0f;
    }
}

// ---------------- main: split-K MFMA GEMM, counted-vmcnt DMA pipeline ------
// 4 LDS buffers, DMA issued 3 steps ahead, ONE raw s_barrier per step,
// steady-state s_waitcnt vmcnt(4) (2 loads/wave/step in flight x2 steps).
// Buffer written at step s+3 was consumed at step s-1; barrier(s) separates.
template<int NSLABS>
static __device__ __forceinline__ void run_gemm(
    int nplanes, int p0, const unsigned short* asrc, int astride,
    const unsigned short* __restrict__ wt, unsigned short* __restrict__ slices,
    int chunk, int b0, int o0, int t,
    unsigned short (*B_lds)[64 * 64], const float* h_s)
{
    constexpr int LOG2S = (NSLABS == 4) ? 2 : 1;
    const int lane = t & 63, wave = t >> 6;
    const int wm = wave >> 1, wn = wave & 1;
    const int qg = lane >> 4, ncol = lane & 15;

    // lane-constant DMA source pieces (swizzle folded into source gather)
    const int drow = lane >> 3;                  // 0..7
    const int dcol = ((lane & 7) ^ drow) * 8;    // swizzled k-block (shorts)
    const int nsteps = nplanes * NSLABS;

    auto dmaB = [&](int s) {
        const int plane = p0 + (s >> LOG2S);
        const int i0    = (s & (NSLABS - 1)) * 64;
        const int buf   = s & 3;
        const unsigned short* gp = wt + (size_t)plane * PLANE_SZ
            + (size_t)(o0 + wave * 16 + drow) * 256 + i0 + dcol;
        __builtin_amdgcn_global_load_lds(
            (const __attribute__((address_space(1))) unsigned int*)gp,
            (__attribute__((address_space(3))) unsigned int*)&B_lds[buf][wave * 16 * 64],
            16, 0, 0);
        __builtin_amdgcn_global_load_lds(
            (const __attribute__((address_space(1))) unsigned int*)(gp + 8 * 256),
            (__attribute__((address_space(3))) unsigned int*)&B_lds[buf][(wave * 16 + 8) * 64],
            16, 0, 0);
    };

    // A fragments: loaded once (oldest VMEM ops -> retire before DMA waits)
    bf16x8 xf[NSLABS][2][2];
    #pragma unroll
    for (int sl = 0; sl < NSLABS; ++sl)
        #pragma unroll
        for (int ks = 0; ks < 2; ++ks)
            #pragma unroll
            for (int mf = 0; mf < 2; ++mf)
                xf[sl][ks][mf] = *(const bf16x8*)(asrc
                    + (size_t)(b0 + wm * 32 + mf * 16 + ncol) * astride
                    + sl * 64 + ks * 32 + qg * 8);

    f32x4 acc[2][2] = {};
    f32x4 pacc[2][2];
    float hv[2][4];

    // prologue: fill 3-deep pipeline
    dmaB(0); dmaB(1);
    if (nsteps > 2) dmaB(2);

    for (int pl = 0; pl < nplanes; ++pl) {
        #pragma unroll
        for (int sl = 0; sl < NSLABS; ++sl) {
            const int s = pl * NSLABS + sl;

            // wait only for THIS step's 2 loads (leave later steps in flight)
            if (s <= nsteps - 3)      wait_vmcnt<4>();
            else if (s == nsteps - 2) wait_vmcnt<2>();
            else                      wait_vmcnt<0>();
            __builtin_amdgcn_s_barrier();
            asm volatile("" ::: "memory");           // no LDS reads above barrier

            if (sl == 0) {
                #pragma unroll
                for (int mf = 0; mf < 2; ++mf)
                    #pragma unroll
                    for (int r = 0; r < 4; ++r)
                        hv[mf][r] = h_s[(wm * 32 + mf * 16 + qg * 4 + r) * 8 + pl];
                #pragma unroll
                for (int a = 0; a < 2; ++a)
                    #pragma unroll
                    for (int bq = 0; bq < 2; ++bq)
                        pacc[a][bq] = (f32x4){0.f, 0.f, 0.f, 0.f};
            }

            const int buf = s & 3;
            #pragma unroll
            for (int ks = 0; ks < 2; ++ks) {
                bf16x8 bfr[2];
                #pragma unroll
                for (int nf = 0; nf < 2; ++nf) {
                    int n = wn * 32 + nf * 16 + ncol;
                    bfr[nf] = *(const bf16x8*)&B_lds[buf][(n * 8 + ((ks * 4 + qg) ^ (n & 7))) * 8];
                }
                #pragma unroll
                for (int mf = 0; mf < 2; ++mf)
                    #pragma unroll
                    for (int nf = 0; nf < 2; ++nf)
                        pacc[mf][nf] = __builtin_amdgcn_mfma_f32_16x16x32_bf16(
                            xf[sl][ks][mf], bfr[nf], pacc[mf][nf], 0, 0, 0);
            }

            if (sl == NSLABS - 1) {              // fold plane into acc with h scale
                #pragma unroll
                for (int mf = 0; mf < 2; ++mf)
                    #pragma unroll
                    for (int nf = 0; nf < 2; ++nf)
                        #pragma unroll
                        for (int r = 0; r < 4; ++r)
                            acc[mf][nf][r] += hv[mf][r] * pacc[mf][nf][r];
            }

            // refill: target buffer (s+3)&3 was consumed at step s-1,
            // all waves passed barrier(s) after finishing it -> safe
            if (s + 3 < nsteps) dmaB(s + 3);
        }
    }

    unsigned short* slice = slices + (size_t)chunk * OUT_ELEMS;
    #pragma unroll
    for (int mf = 0; mf < 2; ++mf)
        #pragma unroll
        for (int nf = 0; nf < 2; ++nf)
            #pragma unroll
            for (int r = 0; r < 4; ++r) {
                int row = b0 + wm * 32 + mf * 16 + qg * 4 + r;
                int col = o0 + wn * 32 + nf * 16 + ncol;
                slice[(size_t)row * OUT_DIM + col] = f2bf(acc[mf][nf][r]);
            }
}

__global__ __launch_bounds__(256, 3)
void hyper_main_kernel(const unsigned short* __restrict__ wt,
                       unsigned short* __restrict__ slices) {
    __shared__ __align__(16) unsigned short B_lds[4][64 * 64];   // 32 KB
    __shared__ float h_s[512];                                   // 64 rows x 8 planes

    const int bx    = blockIdx.x;            // 18 * 32 = 576 (single residency round)
    const int chunk = bx >> 5;
    const int rem   = bx & 31;
    const int b0    = (rem >> 2) * 64;
    const int o0    = (rem & 3) * 64;
    const int t     = threadIdx.x;

    const int p0 = (chunk < 16) ? chunk * 8 : (chunk == 16 ? 128 : 130);

    // stage per-plane h scales (chunks 16/17 read 1.0 from g_h ones-lanes)
    h_s[t]       = g_h[(b0      + (t >> 3)) * H_STRIDE + p0 + (t & 7)];
    h_s[256 + t] = g_h[(b0 + 32 + (t >> 3)) * H_STRIDE + p0 + (t & 7)];
    __syncthreads();

    if (chunk < 17)
        run_gemm<4>(chunk < 16 ? 8 : 2, p0, g_xbf, IN_DIM,
                    wt, slices, chunk, b0, o0, t, B_lds, h_s);
    else
        run_gemm<2>(1, p0, g_hbf, HIDDEN,
                    wt, slices, chunk, b0, o0, t, B_lds, h_s);
}

// ---------------- reduce: sum bf16 slices + bias vectors -------------------
__global__ void hyper_reduce_kernel(const unsigned short* __restrict__ slices,
                                    const float* __restrict__ base_bias,
                                    const float* __restrict__ b2,
                                    float* __restrict__ out) {
    int i = blockIdx.x * 256 + threadIdx.x;        // float4 index, 32768 total
    int o = (i & 63) * 4;
    float4 bb = *(const float4*)(base_bias + o);
    float4 c2 = *(const float4*)(b2 + 65536 + o);
    float4 a;
    a.x = bb.x + c2.x; a.y = bb.y + c2.y; a.z = bb.z + c2.z; a.w = bb.w + c2.w;
    #pragma unroll
    for (int c = 0; c < NCHUNKS; ++c) {
        ushort4 v = *(const ushort4*)(slices + (size_t)c * OUT_ELEMS + (size_t)i * 4);
        a.x += bf2f(v.x); a.y += bf2f(v.y); a.z += bf2f(v.z); a.w += bf2f(v.w);
    }
    ((float4*)out)[i] = a;
}

// ---------------- launch ---------------------------------------------------
extern "C" void kernel_launch(void* const* d_in, const int* in_sizes, int n_in,
                              void* d_out, int out_size, void* d_ws, size_t ws_size,
                              hipStream_t stream) {
    const float* x           = (const float*)d_in[0];
    const float* cond        = (const float*)d_in[1];
    const float* base_weight = (const float*)d_in[2];
    const float* base_bias   = (const float*)d_in[3];
    const float* w1          = (const float*)d_in[4];
    const float* b1          = (const float*)d_in[5];
    const float* w2          = (const float*)d_in[6];
    const float* b2          = (const float*)d_in[7];
    float* out = (float*)d_out;
    unsigned short* ws = (unsigned short*)d_ws;     // 131 planes + 18 slices = 21.9 MB

    hyper_prep_kernel<<<2360, 256, 0, stream>>>(x, cond, base_weight, w1, b1, w2, b2, ws);
    hyper_main_kernel<<<NCHUNKS * 32, 256, 0, stream>>>(ws, ws + SLICE_OFF);
    hyper_reduce_kernel<<<OUT_ELEMS / 4 / 256, 256, 0, stream>>>(ws + SLICE_OFF, base_bias, b2, out);
}